// Round 1
// baseline (1688.575 us; speedup 1.0000x reference)
//
#include <hip/hip_runtime.h>

// VQ-VAE codebook quantize: z (8,256,16,32,32) f32, codebook (1024,256) f32.
// Outputs (concat in d_out, all f32): quantized (8,256,16,32,32),
// st (== quantized forward), indices (8,16,32,32) stored as float.

constexpr int Bn  = 8;
constexpr int Dd  = 256;
constexpr int SPB = 16384;          // t*h*w = 16*32*32
constexpr int Nn  = Bn * SPB;       // 131072 tokens
constexpr int Kk  = 1024;           // codes
constexpr int TM  = 128;            // tokens per block
constexpr int TK  = 128;            // codes per chunk
constexpr int DK  = 16;             // d per staging chunk
constexpr int BPAD = 4;             // LDS pad for transposed B store

__global__ __launch_bounds__(64) void cnorm_k(const float* __restrict__ cb,
                                              float* __restrict__ cn) {
    const int k = blockIdx.x;
    const int l = threadIdx.x;
    const float* row = cb + (size_t)k * Dd;
    float s = 0.f;
    #pragma unroll
    for (int c = 0; c < Dd; c += 64) { float v = row[c + l]; s += v * v; }
    #pragma unroll
    for (int off = 32; off > 0; off >>= 1) s += __shfl_down(s, off, 64);
    if (l == 0) cn[k] = s;
}

// body of the 8x8 micro-kernel for one d-step; WITH_ZN also accumulates ||z||^2
#define MICRO_STEP(WITH_ZN)                                                    \
    {                                                                          \
        float4 a0 = *(const float4*)&As[d][ty * 8];                            \
        float4 a1 = *(const float4*)&As[d][ty * 8 + 4];                        \
        float4 b0 = *(const float4*)&Bs[d][tx * 8];                            \
        float4 b1 = *(const float4*)&Bs[d][tx * 8 + 4];                        \
        float a[8] = {a0.x, a0.y, a0.z, a0.w, a1.x, a1.y, a1.z, a1.w};         \
        float bb[8] = {b0.x, b0.y, b0.z, b0.w, b1.x, b1.y, b1.z, b1.w};        \
        _Pragma("unroll")                                                      \
        for (int i = 0; i < 8; i++) {                                          \
            _Pragma("unroll")                                                  \
            for (int j = 0; j < 8; j++) acc[i][j] += a[i] * bb[j];             \
            if (WITH_ZN) zn[i] += a[i] * a[i];                                 \
        }                                                                      \
    }

__global__ __launch_bounds__(256) void vq_k(const float* __restrict__ z,
                                            const float* __restrict__ cb,
                                            const float* __restrict__ cn,
                                            float* __restrict__ out) {
    __shared__ float As[DK][TM];        // [d][token]
    __shared__ float Bs[DK][TK + BPAD]; // [d][code], padded
    __shared__ int   ids[TM];

    const int tid = threadIdx.x;
    const int tx  = tid & 15;           // code group
    const int ty  = tid >> 4;           // token group
    const int blk = blockIdx.x;
    const int b   = blk >> 7;           // batch
    const int sb  = (blk & 127) * TM;   // spatial base within batch

    const float* zb = z + (size_t)b * Dd * SPB + sb;

    float bestv[8];
    int   besti[8];
    float zn[8];
    #pragma unroll
    for (int i = 0; i < 8; i++) { bestv[i] = 3.4e38f; besti[i] = 0; zn[i] = 0.f; }

    const int am = tid & 127, ad = tid >> 7;  // A staging: token, d-offset
    const int bd = tid & 15,  bk = tid >> 4;  // B staging: d, code

    for (int cc = 0; cc < Kk / TK; cc++) {
        float acc[8][8];
        #pragma unroll
        for (int i = 0; i < 8; i++)
            #pragma unroll
            for (int j = 0; j < 8; j++) acc[i][j] = 0.f;

        for (int dc = 0; dc < Dd / DK; dc++) {
            #pragma unroll
            for (int r = 0; r < 8; r++) {
                const int d = ad + r * 2;
                As[d][am] = zb[(size_t)(dc * DK + d) * SPB + am];
            }
            #pragma unroll
            for (int r = 0; r < 8; r++) {
                const int k = bk + r * 16;
                Bs[bd][k] = cb[(size_t)(cc * TK + k) * Dd + dc * DK + bd];
            }
            __syncthreads();
            if (cc == 0) {
                #pragma unroll
                for (int d = 0; d < DK; d++) MICRO_STEP(1)
            } else {
                #pragma unroll
                for (int d = 0; d < DK; d++) MICRO_STEP(0)
            }
            __syncthreads();
        }

        // d2 = (znorm - 2*dot) + cnorm, replicating reference fp32 op order.
        const float* cnp = cn + cc * TK + tx * 8;
        float4 c0 = *(const float4*)cnp;
        float4 c1 = *(const float4*)(cnp + 4);
        float cv[8] = {c0.x, c0.y, c0.z, c0.w, c1.x, c1.y, c1.z, c1.w};
        #pragma unroll
        for (int i = 0; i < 8; i++) {
            #pragma unroll
            for (int j = 0; j < 8; j++) {
                float t  = zn[i] - 2.0f * acc[i][j];
                float d2 = t + cv[j];
                int   ix = cc * TK + tx * 8 + j;
                if (d2 < bestv[i]) { bestv[i] = d2; besti[i] = ix; }  // strict <: first index wins
            }
        }
    }

    // cross-lane argmin over the 16 code-group lanes (same wave), tie-break low idx
    #pragma unroll
    for (int i = 0; i < 8; i++) {
        float v  = bestv[i];
        int   ix = besti[i];
        #pragma unroll
        for (int off = 8; off > 0; off >>= 1) {
            float ov = __shfl_down(v, off, 16);
            int   oi = __shfl_down(ix, off, 16);
            if (ov < v || (ov == v && oi < ix)) { v = ov; ix = oi; }
        }
        if (tx == 0) ids[ty * 8 + i] = ix;
    }
    __syncthreads();

    // epilogue: write indices (as float) + gather codebook rows for quantized & st
    if (tid < TM) out[(size_t)2 * Nn * Dd + (size_t)blk * TM + tid] = (float)ids[tid];

    const int m  = tid & 127;
    const int cg = tid >> 7;            // 0..1: which half of the channels
    const int myidx = ids[m];
    const float* crow = cb + (size_t)myidx * Dd + cg * 128;
    float* q  = out + (size_t)b * Dd * SPB + (size_t)cg * 128 * SPB + sb + m;
    float* st = q + (size_t)Nn * Dd;
    #pragma unroll 8
    for (int r = 0; r < 128; r++) {
        const float v = crow[r];
        q[(size_t)r * SPB]  = v;
        st[(size_t)r * SPB] = v;
    }
}

extern "C" void kernel_launch(void* const* d_in, const int* in_sizes, int n_in,
                              void* d_out, int out_size, void* d_ws, size_t ws_size,
                              hipStream_t stream) {
    const float* z  = (const float*)d_in[0];
    const float* cb = (const float*)d_in[1];
    float* out = (float*)d_out;
    float* cn  = (float*)d_ws;   // 1024 floats of ||e_k||^2

    cnorm_k<<<Kk, 64, 0, stream>>>(cb, cn);
    vq_k<<<Nn / TM, 256, 0, stream>>>(z, cb, cn, out);
}

// Round 3
// 800.052 us; speedup vs baseline: 2.1106x; 2.1106x over previous
//
#include <hip/hip_runtime.h>
#include <stdint.h>

// VQ-VAE codebook quantize: z (8,256,16,32,32) f32, codebook (1024,256) f32.
// Outputs (concat in d_out, f32): quantized, st (== quantized fwd), indices.
// R3: single-term bf16 MFMA approximate sweep + window-collect + exact fp32
// rescore (R1-proven arithmetic) for reference-bit-identical argmin.

constexpr int Dd  = 256;
constexpr int SPB = 16384;          // 16*32*32
constexpr int Nn  = 131072;         // 8*SPB tokens
constexpr int Kk  = 1024;
constexpr int CCAP = 32;            // candidate cap per token
#define WWIN 2.0e-3f                // collect window; >= 2x hard error bound

typedef short short8 __attribute__((ext_vector_type(8)));
typedef float v4f    __attribute__((ext_vector_type(4)));

__device__ __forceinline__ unsigned bf16pk(float a, float b){  // RNE pack 2xbf16
  unsigned ua = __float_as_uint(a), ub = __float_as_uint(b);
  ua = (ua + 0x7fffu + ((ua >> 16) & 1u)) >> 16;
  ub = (ub + 0x7fffu + ((ub >> 16) & 1u)) & 0xffff0000u;
  return ua | ub;
}
__device__ __forceinline__ short8 frg(uint4 u){
  union { uint4 a; short8 b; } x; x.a = u; return x.b;
}
__device__ __forceinline__ v4f mfma16(short8 a, short8 b, v4f c){
  return __builtin_amdgcn_mfma_f32_16x16x32_bf16(a, b, c, 0, 0, 0);
}
__device__ __forceinline__ void dma16(const void* g, void* l){
  __builtin_amdgcn_global_load_lds((const __attribute__((address_space(1))) void*)g,
                                   (__attribute__((address_space(3))) void*)l, 16, 0, 0);
}

// ---------- prepass: ||e_k||^2 (R1-proven) ----------
__global__ __launch_bounds__(64) void cnorm_k(const float* __restrict__ cb,
                                              float* __restrict__ cn){
  const int k = blockIdx.x, l = threadIdx.x;
  const float* row = cb + (size_t)k * Dd;
  float s = 0.f;
  #pragma unroll
  for (int c = 0; c < Dd; c += 64){ float v = row[c + l]; s += v * v; }
  #pragma unroll
  for (int off = 32; off > 0; off >>= 1) s += __shfl_down(s, off, 64);
  if (l == 0) cn[k] = s;
}

// ---------- prepass: codebook -> bf16 hi fragment plane ----------
// Bg: [cc 0..3][dc 0..7][kq 0..3][n 0..255] x 16B
__global__ __launch_bounds__(256) void cconv_k(const float* __restrict__ cb,
                                               uint4* __restrict__ Bg){
  const int cc = blockIdx.x, n = threadIdx.x;
  const float* row = cb + (size_t)(cc * 256 + n) * Dd;
  for (int dc = 0; dc < 8; dc++){
    float v[32];
    const float4* rp = (const float4*)(row + dc * 32);
    #pragma unroll
    for (int q = 0; q < 8; q++){
      float4 f = rp[q]; v[4*q]=f.x; v[4*q+1]=f.y; v[4*q+2]=f.z; v[4*q+3]=f.w;
    }
    unsigned hv[16];
    #pragma unroll
    for (int p = 0; p < 16; p++) hv[p] = bf16pk(v[2*p], v[2*p+1]);
    size_t base = ((size_t)cc * 8 + dc) * 1024;
    #pragma unroll
    for (int kq = 0; kq < 4; kq++)
      Bg[base + (size_t)kq*256 + n] = make_uint4(hv[4*kq],hv[4*kq+1],hv[4*kq+2],hv[4*kq+3]);
  }
}

// ---------- prepass: z -> bf16 hi fragment plane + ||z||^2 ----------
// Ag: [blk 0..1023][dc 0..7][kq 0..3][m 0..127] x 16B
__global__ __launch_bounds__(256) void zconv_k(const float* __restrict__ z,
                                               uint4* __restrict__ Ag,
                                               float* __restrict__ znG){
  __shared__ float znp[256];
  const int tid = threadIdx.x, blk = blockIdx.x;
  const int b = blk >> 7, sb = (blk & 127) * 128;
  const int m = tid & 127, kqh = tid >> 7;
  const float* zb = z + (size_t)b * Dd * SPB + sb + m;
  float zsum = 0.f;
  for (int dc = 0; dc < 8; dc++){
    float v[16];
    #pragma unroll
    for (int s = 0; s < 16; s++) v[s] = zb[(size_t)(dc*32 + kqh*16 + s) * SPB];
    #pragma unroll
    for (int s = 0; s < 16; s++) zsum += v[s] * v[s];
    unsigned hv[8];
    #pragma unroll
    for (int p = 0; p < 8; p++) hv[p] = bf16pk(v[2*p], v[2*p+1]);
    size_t base = ((size_t)blk * 8 + dc) * 512;
    Ag[base + (size_t)(kqh*2+0)*128 + m] = make_uint4(hv[0],hv[1],hv[2],hv[3]);
    Ag[base + (size_t)(kqh*2+1)*128 + m] = make_uint4(hv[4],hv[5],hv[6],hv[7]);
  }
  znp[tid] = zsum;
  __syncthreads();
  if (tid < 128) znG[blk*128 + tid] = znp[tid] + znp[tid + 128];
}

// ---------- main: approx MFMA sweep + collect + exact rescore + gather ----------
__global__ __launch_bounds__(256, 2) void vq_k2(const uint4* __restrict__ Ag,
                                                const uint4* __restrict__ Bg,
                                                const float* __restrict__ znG,
                                                const float* __restrict__ cnG,
                                                const float* __restrict__ cb,
                                                const float* __restrict__ z,
                                                float* __restrict__ out){
  __shared__ uint4 Asw[512];                 // [kq][m]    8 KB
  __shared__ uint4 Bsw[1024];                // [kq][n]   16 KB
  __shared__ float znS[128];
  __shared__ float bestV[2][128];
  __shared__ int   bestI[2][128];
  __shared__ int   cnt[128];
  __shared__ unsigned short cand[128][CCAP]; // 8 KB
  __shared__ int   ids[128];

  const int tid = threadIdx.x, blk = blockIdx.x;
  const int b = blk >> 7, sb = (blk & 127) * 128;
  const int w = tid >> 6, ln = tid & 63;
  const int lq = ln >> 4, li = ln & 15;
  const int tH = w & 1, cH = w >> 1;

  if (tid < 128){ znS[tid] = znG[blk*128 + tid]; cnt[tid] = 0; ids[tid] = 0; }
  bestV[tid >> 7][tid & 127] = 3.0e38f;
  bestI[tid >> 7][tid & 127] = 0x7fffffff;
  __syncthreads();

  for (int cc = 0; cc < 4; cc++){
    v4f acc[4][8];
    const v4f vz = {0.f, 0.f, 0.f, 0.f};
    #pragma unroll
    for (int mi = 0; mi < 4; mi++)
      #pragma unroll
      for (int ni = 0; ni < 8; ni++) acc[mi][ni] = vz;

    float cnv[8];
    #pragma unroll
    for (int ni = 0; ni < 8; ni++) cnv[ni] = cnG[cc*256 + cH*128 + ni*16 + li];

    for (int dc = 0; dc < 8; dc++){
      const uint4* Ab = Ag + ((size_t)blk * 8 + dc) * 512;
      const uint4* Bb = Bg + ((size_t)cc  * 8 + dc) * 1024;
      #pragma unroll
      for (int i = 0; i < 2; i++)
        dma16(Ab + (w*2 + i)*64 + ln, &Asw[(w*2 + i)*64]);
      #pragma unroll
      for (int i = 0; i < 4; i++)
        dma16(Bb + (w*4 + i)*64 + ln, &Bsw[(w*4 + i)*64]);
      __syncthreads();

      short8 aH[4];
      #pragma unroll
      for (int mi = 0; mi < 4; mi++)
        aH[mi] = frg(Asw[lq*128 + tH*64 + mi*16 + li]);
      #pragma unroll
      for (int ni = 0; ni < 8; ni++){
        short8 bH = frg(Bsw[lq*256 + cH*128 + ni*16 + li]);
        #pragma unroll
        for (int mi = 0; mi < 4; mi++)
          acc[mi][ni] = mfma16(aH[mi], bH, acc[mi][ni]);
      }
      __syncthreads();
    }

    // chunk reduce -> running min per row (drives thresholds only)
    #pragma unroll
    for (int mi = 0; mi < 4; mi++){
      #pragma unroll
      for (int r = 0; r < 4; r++){
        const int row = tH*64 + mi*16 + lq*4 + r;
        const float zn = znS[row];
        float bv = 3.0e38f; int bi = 0x7fffffff;
        #pragma unroll
        for (int ni = 0; ni < 8; ni++){
          float t  = zn - 2.0f * acc[mi][ni][r];
          float d2 = t + cnv[ni];
          const int code = cc*256 + cH*128 + ni*16 + li;
          if (d2 < bv || (d2 == bv && code < bi)){ bv = d2; bi = code; }
        }
        #pragma unroll
        for (int off = 1; off < 16; off <<= 1){
          float ov = __shfl_xor(bv, off, 16);
          int   oi = __shfl_xor(bi, off, 16);
          if (ov < bv || (ov == bv && oi < bi)){ bv = ov; bi = oi; }
        }
        if (li == 0){
          if (bv < bestV[cH][row] || (bv == bestV[cH][row] && bi < bestI[cH][row])){
            bestV[cH][row] = bv; bestI[cH][row] = bi;
          }
        }
      }
    }
    __syncthreads();

    // collect all codes within WWIN of running global min
    #pragma unroll
    for (int mi = 0; mi < 4; mi++){
      #pragma unroll
      for (int r = 0; r < 4; r++){
        const int row = tH*64 + mi*16 + lq*4 + r;
        const float thr = fminf(bestV[0][row], bestV[1][row]) + WWIN;
        const float zn = znS[row];
        #pragma unroll
        for (int ni = 0; ni < 8; ni++){
          float t  = zn - 2.0f * acc[mi][ni][r];
          float d2 = t + cnv[ni];
          if (d2 <= thr){
            const int code = cc*256 + cH*128 + ni*16 + li;
            int pos = atomicAdd(&cnt[row], 1);
            if (pos < CCAP) cand[row][pos] = (unsigned short)code;
          }
        }
      }
    }
    __syncthreads();
  }

  // provisional ids from approx min (used only if a row somehow has 0 cands)
  if (tid < 128){
    float v0 = bestV[0][tid], v1 = bestV[1][tid];
    int   i0 = bestI[0][tid], i1 = bestI[1][tid];
    ids[tid] = (v1 < v0 || (v1 == v0 && i1 < i0)) ? i1 : i0;
  }
  __syncthreads();

  // exact fp32 rescore of candidates — bitwise R1 arithmetic:
  // zn, dot: linear-d FMA chains; t = zn - 2*dot (exact mul); d2 = t + cn.
  if (tid < 128){
    const int row = tid;
    int n = cnt[row]; if (n > CCAP) n = CCAP;
    const float* zr = z + (size_t)b * Dd * SPB + sb + row;
    float bv = 3.4e38f; int bi = 0x7fffffff;
    float znl = 0.f;
    for (int g = 0; g < n; g += 4){
      int idxs[4]; const float* cr[4];
      #pragma unroll
      for (int s = 0; s < 4; s++){
        int slot = g + s; if (slot >= n) slot = n - 1;
        idxs[s] = cand[row][slot];
        cr[s] = cb + (size_t)idxs[s] * Dd;
      }
      float a0=0.f, a1=0.f, a2=0.f, a3=0.f, za=0.f;
      for (int d = 0; d < Dd; d += 8){
        float zv[8];
        #pragma unroll
        for (int j = 0; j < 8; j++) zv[j] = zr[(size_t)(d + j) * SPB];
        float cv[4][8];
        #pragma unroll
        for (int s = 0; s < 4; s++){
          float4 ca = *(const float4*)(cr[s] + d);
          float4 cb4 = *(const float4*)(cr[s] + d + 4);
          cv[s][0]=ca.x; cv[s][1]=ca.y; cv[s][2]=ca.z; cv[s][3]=ca.w;
          cv[s][4]=cb4.x; cv[s][5]=cb4.y; cv[s][6]=cb4.z; cv[s][7]=cb4.w;
        }
        #pragma unroll
        for (int j = 0; j < 8; j++){
          if (g == 0) za = fmaf(zv[j], zv[j], za);
          a0 = fmaf(zv[j], cv[0][j], a0);
          a1 = fmaf(zv[j], cv[1][j], a1);
          a2 = fmaf(zv[j], cv[2][j], a2);
          a3 = fmaf(zv[j], cv[3][j], a3);
        }
      }
      if (g == 0) znl = za;
      float av[4] = {a0, a1, a2, a3};
      #pragma unroll
      for (int s = 0; s < 4; s++){
        if (g + s < n){
          float t  = znl - 2.0f * av[s];
          float d2 = t + cnG[idxs[s]];
          if (d2 < bv || (d2 == bv && idxs[s] < bi)){ bv = d2; bi = idxs[s]; }
        }
      }
    }
    if (n > 0) ids[row] = bi;
  }
  __syncthreads();

  // index write + gather epilogue (R1-proven)
  if (tid < 128) out[(size_t)2 * Nn * Dd + (size_t)blk * 128 + tid] = (float)ids[tid];

  const int m = tid & 127, cg = tid >> 7;
  const int myidx = ids[m];
  const float* crow = cb + (size_t)myidx * Dd + cg * 128;
  float* q  = out + (size_t)b * Dd * SPB + (size_t)cg * 128 * SPB + sb + m;
  float* st = q + (size_t)Nn * Dd;
  #pragma unroll 8
  for (int r2 = 0; r2 < 128; r2++){
    const float v = crow[r2];
    q[(size_t)r2 * SPB]  = v;
    st[(size_t)r2 * SPB] = v;
  }
}

// ================= R1 fp32 fallback (used if ws too small) =================
#define MICRO_STEP(WITH_ZN)                                                    \
    {                                                                          \
        float4 a0 = *(const float4*)&As[d][ty * 8];                            \
        float4 a1 = *(const float4*)&As[d][ty * 8 + 4];                        \
        float4 b0 = *(const float4*)&Bs[d][tx * 8];                            \
        float4 b1 = *(const float4*)&Bs[d][tx * 8 + 4];                        \
        float a[8] = {a0.x, a0.y, a0.z, a0.w, a1.x, a1.y, a1.z, a1.w};         \
        float bb[8] = {b0.x, b0.y, b0.z, b0.w, b1.x, b1.y, b1.z, b1.w};        \
        _Pragma("unroll")                                                      \
        for (int i = 0; i < 8; i++) {                                          \
            _Pragma("unroll")                                                  \
            for (int j = 0; j < 8; j++) acc[i][j] += a[i] * bb[j];             \
            if (WITH_ZN) zn[i] += a[i] * a[i];                                 \
        }                                                                      \
    }

__global__ __launch_bounds__(256) void vq_k(const float* __restrict__ z,
                                            const float* __restrict__ cb,
                                            const float* __restrict__ cn,
                                            float* __restrict__ out){
  __shared__ float As[16][128];
  __shared__ float Bs[16][132];
  __shared__ int   idsf[128];
  const int tid = threadIdx.x;
  const int tx = tid & 15, ty = tid >> 4;
  const int blk = blockIdx.x;
  const int b = blk >> 7, sb = (blk & 127) * 128;
  const float* zb = z + (size_t)b * Dd * SPB + sb;
  float bestv[8]; int besti[8]; float zn[8];
  #pragma unroll
  for (int i = 0; i < 8; i++){ bestv[i] = 3.4e38f; besti[i] = 0; zn[i] = 0.f; }
  const int am = tid & 127, ad = tid >> 7;
  const int bd = tid & 15,  bk = tid >> 4;
  for (int cc = 0; cc < 8; cc++){
    float acc[8][8];
    #pragma unroll
    for (int i = 0; i < 8; i++)
      #pragma unroll
      for (int j = 0; j < 8; j++) acc[i][j] = 0.f;
    for (int dc = 0; dc < 16; dc++){
      #pragma unroll
      for (int r = 0; r < 8; r++){
        const int d = ad + r * 2;
        As[d][am] = zb[(size_t)(dc*16 + d) * SPB + am];
      }
      #pragma unroll
      for (int r = 0; r < 8; r++){
        const int k = bk + r * 16;
        Bs[bd][k] = cb[(size_t)(cc*128 + k) * Dd + dc*16 + bd];
      }
      __syncthreads();
      if (cc == 0){
        #pragma unroll
        for (int d = 0; d < 16; d++) MICRO_STEP(1)
      } else {
        #pragma unroll
        for (int d = 0; d < 16; d++) MICRO_STEP(0)
      }
      __syncthreads();
    }
    const float* cnp = cn + cc*128 + tx*8;
    float4 c0 = *(const float4*)cnp;
    float4 c1 = *(const float4*)(cnp + 4);
    float cv[8] = {c0.x, c0.y, c0.z, c0.w, c1.x, c1.y, c1.z, c1.w};
    #pragma unroll
    for (int i = 0; i < 8; i++){
      #pragma unroll
      for (int j = 0; j < 8; j++){
        float t  = zn[i] - 2.0f * acc[i][j];
        float d2 = t + cv[j];
        int   ix = cc*128 + tx*8 + j;
        if (d2 < bestv[i]){ bestv[i] = d2; besti[i] = ix; }
      }
    }
  }
  #pragma unroll
  for (int i = 0; i < 8; i++){
    float v = bestv[i]; int ix = besti[i];
    #pragma unroll
    for (int off = 8; off > 0; off >>= 1){
      float ov = __shfl_down(v, off, 16);
      int   oi = __shfl_down(ix, off, 16);
      if (ov < v || (ov == v && oi < ix)){ v = ov; ix = oi; }
    }
    if (tx == 0) idsf[ty*8 + i] = ix;
  }
  __syncthreads();
  if (tid < 128) out[(size_t)2*Nn*Dd + (size_t)blk*128 + tid] = (float)idsf[tid];
  const int m = tid & 127, cg = tid >> 7;
  const int myidx = idsf[m];
  const float* crow = cb + (size_t)myidx * Dd + cg*128;
  float* q  = out + (size_t)b * Dd * SPB + (size_t)cg * 128 * SPB + sb + m;
  float* st = q + (size_t)Nn * Dd;
  #pragma unroll 8
  for (int r = 0; r < 128; r++){
    const float v = crow[r];
    q[(size_t)r * SPB]  = v;
    st[(size_t)r * SPB] = v;
  }
}

// ---------- launcher ----------
extern "C" void kernel_launch(void* const* d_in, const int* in_sizes, int n_in,
                              void* d_out, int out_size, void* d_ws, size_t ws_size,
                              hipStream_t stream){
  const float* z  = (const float*)d_in[0];
  const float* cb = (const float*)d_in[1];
  float* out = (float*)d_out;

  const size_t AG_B = (size_t)1024 * 8 * 512 * 16;    // 64 MiB
  const size_t BG_B = (size_t)4 * 8 * 1024 * 16;      // 512 KiB
  const size_t ZN_B = (size_t)Nn * 4;                 // 512 KiB
  const size_t CN_B = (size_t)Kk * 4;                 // 4 KiB
  const size_t NEED = AG_B + BG_B + ZN_B + CN_B;

  if (ws_size >= NEED){
    uint8_t* ws = (uint8_t*)d_ws;
    uint4* Ag  = (uint4*)ws;
    uint4* Bg  = (uint4*)(ws + AG_B);
    float* znG = (float*)(ws + AG_B + BG_B);
    float* cnG = (float*)(ws + AG_B + BG_B + ZN_B);
    cnorm_k<<<Kk, 64, 0, stream>>>(cb, cnG);
    cconv_k<<<4, 256, 0, stream>>>(cb, Bg);
    zconv_k<<<Nn/128, 256, 0, stream>>>(z, Ag, znG);
    vq_k2<<<Nn/128, 256, 0, stream>>>(Ag, Bg, znG, cnG, cb, z, out);
  } else {
    float* cn = (float*)d_ws;
    cnorm_k<<<Kk, 64, 0, stream>>>(cb, cn);
    vq_k<<<Nn/128, 256, 0, stream>>>(z, cb, cn, out);
  }
}

// Round 4
// 786.803 us; speedup vs baseline: 2.1461x; 1.0168x over previous
//
#include <hip/hip_runtime.h>
#include <stdint.h>

// VQ-VAE codebook quantize: z (8,256,16,32,32) f32, codebook (1024,256) f32.
// Outputs (concat in d_out, f32): quantized, st (== quantized fwd), indices.
// R4: phase-split — [sweep+collect] / [exact rescore] / [LDS-transpose gather]
// so each phase runs at full-grid concurrency. Numerics identical to R3 (passed).

constexpr int Dd  = 256;
constexpr int SPB = 16384;          // 16*32*32
constexpr int Nn  = 131072;         // 8*SPB tokens
constexpr int Kk  = 1024;
constexpr int CCAP = 16;            // candidate cap per token (avg ~1.2, P(>16)~0)
#define WWIN 2.0e-3f                // collect window; >= 2x approx error bound

typedef short short8 __attribute__((ext_vector_type(8)));
typedef float v4f    __attribute__((ext_vector_type(4)));

__device__ __forceinline__ unsigned bf16pk(float a, float b){  // RNE pack 2xbf16
  unsigned ua = __float_as_uint(a), ub = __float_as_uint(b);
  ua = (ua + 0x7fffu + ((ua >> 16) & 1u)) >> 16;
  ub = (ub + 0x7fffu + ((ub >> 16) & 1u)) & 0xffff0000u;
  return ua | ub;
}
__device__ __forceinline__ short8 frg(uint4 u){
  union { uint4 a; short8 b; } x; x.a = u; return x.b;
}
__device__ __forceinline__ v4f mfma16(short8 a, short8 b, v4f c){
  return __builtin_amdgcn_mfma_f32_16x16x32_bf16(a, b, c, 0, 0, 0);
}
__device__ __forceinline__ void dma16(const void* g, void* l){
  __builtin_amdgcn_global_load_lds((const __attribute__((address_space(1))) void*)g,
                                   (__attribute__((address_space(3))) void*)l, 16, 0, 0);
}

// ---------- prepass: ||e_k||^2 ----------
__global__ __launch_bounds__(64) void cnorm_k(const float* __restrict__ cb,
                                              float* __restrict__ cn){
  const int k = blockIdx.x, l = threadIdx.x;
  const float* row = cb + (size_t)k * Dd;
  float s = 0.f;
  #pragma unroll
  for (int c = 0; c < Dd; c += 64){ float v = row[c + l]; s += v * v; }
  #pragma unroll
  for (int off = 32; off > 0; off >>= 1) s += __shfl_down(s, off, 64);
  if (l == 0) cn[k] = s;
}

// ---------- prepass: codebook -> bf16 hi fragment plane ----------
// Bg: [cc 0..3][dc 0..7][kq 0..3][n 0..255] x 16B
__global__ __launch_bounds__(256) void cconv_k(const float* __restrict__ cb,
                                               uint4* __restrict__ Bg){
  const int cc = blockIdx.x, n = threadIdx.x;
  const float* row = cb + (size_t)(cc * 256 + n) * Dd;
  for (int dc = 0; dc < 8; dc++){
    float v[32];
    const float4* rp = (const float4*)(row + dc * 32);
    #pragma unroll
    for (int q = 0; q < 8; q++){
      float4 f = rp[q]; v[4*q]=f.x; v[4*q+1]=f.y; v[4*q+2]=f.z; v[4*q+3]=f.w;
    }
    unsigned hv[16];
    #pragma unroll
    for (int p = 0; p < 16; p++) hv[p] = bf16pk(v[2*p], v[2*p+1]);
    size_t base = ((size_t)cc * 8 + dc) * 1024;
    #pragma unroll
    for (int kq = 0; kq < 4; kq++)
      Bg[base + (size_t)kq*256 + n] = make_uint4(hv[4*kq],hv[4*kq+1],hv[4*kq+2],hv[4*kq+3]);
  }
}

// ---------- prepass: z -> bf16 hi fragment plane + ||z||^2 ----------
// Ag: [blk 0..1023][dc 0..7][kq 0..3][m 0..127] x 16B
__global__ __launch_bounds__(256) void zconv_k(const float* __restrict__ z,
                                               uint4* __restrict__ Ag,
                                               float* __restrict__ znG){
  __shared__ float znp[256];
  const int tid = threadIdx.x, blk = blockIdx.x;
  const int b = blk >> 7, sb = (blk & 127) * 128;
  const int m = tid & 127, kqh = tid >> 7;
  const float* zb = z + (size_t)b * Dd * SPB + sb + m;
  float zsum = 0.f;
  for (int dc = 0; dc < 8; dc++){
    float v[16];
    #pragma unroll
    for (int s = 0; s < 16; s++) v[s] = zb[(size_t)(dc*32 + kqh*16 + s) * SPB];
    #pragma unroll
    for (int s = 0; s < 16; s++) zsum += v[s] * v[s];
    unsigned hv[8];
    #pragma unroll
    for (int p = 0; p < 8; p++) hv[p] = bf16pk(v[2*p], v[2*p+1]);
    size_t base = ((size_t)blk * 8 + dc) * 512;
    Ag[base + (size_t)(kqh*2+0)*128 + m] = make_uint4(hv[0],hv[1],hv[2],hv[3]);
    Ag[base + (size_t)(kqh*2+1)*128 + m] = make_uint4(hv[4],hv[5],hv[6],hv[7]);
  }
  znp[tid] = zsum;
  __syncthreads();
  if (tid < 128) znG[blk*128 + tid] = znp[tid] + znp[tid + 128];
}

// ---------- phase 1: approx MFMA sweep + window collect ----------
__global__ __launch_bounds__(256, 2) void vq_sweep_k(const uint4* __restrict__ Ag,
                                                     const uint4* __restrict__ Bg,
                                                     const float* __restrict__ znG,
                                                     const float* __restrict__ cnG,
                                                     int* __restrict__ cntW,
                                                     unsigned short* __restrict__ candW,
                                                     int* __restrict__ abestW){
  __shared__ uint4 Asw[512];                 //  8 KB
  __shared__ uint4 Bsw[1024];                // 16 KB
  __shared__ float znS[128];
  __shared__ float bestV[2][128];
  __shared__ int   bestI[2][128];
  __shared__ int   cnt[128];
  __shared__ uint4 candU[128][2];            // 128 x 16 ushort, 4 KB

  const int tid = threadIdx.x, blk = blockIdx.x;
  const int w = tid >> 6, ln = tid & 63;
  const int lq = ln >> 4, li = ln & 15;
  const int tH = w & 1, cH = w >> 1;
  unsigned short* cand = (unsigned short*)candU;

  if (tid < 128){ znS[tid] = znG[blk*128 + tid]; cnt[tid] = 0; }
  bestV[tid >> 7][tid & 127] = 3.0e38f;
  bestI[tid >> 7][tid & 127] = 0x7fffffff;
  __syncthreads();

  for (int cc = 0; cc < 4; cc++){
    v4f acc[4][8];
    const v4f vz = {0.f, 0.f, 0.f, 0.f};
    #pragma unroll
    for (int mi = 0; mi < 4; mi++)
      #pragma unroll
      for (int ni = 0; ni < 8; ni++) acc[mi][ni] = vz;

    float cnv[8];
    #pragma unroll
    for (int ni = 0; ni < 8; ni++) cnv[ni] = cnG[cc*256 + cH*128 + ni*16 + li];

    for (int dc = 0; dc < 8; dc++){
      const uint4* Ab = Ag + ((size_t)blk * 8 + dc) * 512;
      const uint4* Bb = Bg + ((size_t)cc  * 8 + dc) * 1024;
      #pragma unroll
      for (int i = 0; i < 2; i++)
        dma16(Ab + (w*2 + i)*64 + ln, &Asw[(w*2 + i)*64]);
      #pragma unroll
      for (int i = 0; i < 4; i++)
        dma16(Bb + (w*4 + i)*64 + ln, &Bsw[(w*4 + i)*64]);
      __syncthreads();

      short8 aH[4];
      #pragma unroll
      for (int mi = 0; mi < 4; mi++)
        aH[mi] = frg(Asw[lq*128 + tH*64 + mi*16 + li]);
      #pragma unroll
      for (int ni = 0; ni < 8; ni++){
        short8 bH = frg(Bsw[lq*256 + cH*128 + ni*16 + li]);
        #pragma unroll
        for (int mi = 0; mi < 4; mi++)
          acc[mi][ni] = mfma16(aH[mi], bH, acc[mi][ni]);
      }
      __syncthreads();
    }

    // chunk reduce -> running min per row
    #pragma unroll
    for (int mi = 0; mi < 4; mi++){
      #pragma unroll
      for (int r = 0; r < 4; r++){
        const int row = tH*64 + mi*16 + lq*4 + r;
        const float zn = znS[row];
        float bv = 3.0e38f; int bi = 0x7fffffff;
        #pragma unroll
        for (int ni = 0; ni < 8; ni++){
          float t  = zn - 2.0f * acc[mi][ni][r];
          float d2 = t + cnv[ni];
          const int code = cc*256 + cH*128 + ni*16 + li;
          if (d2 < bv || (d2 == bv && code < bi)){ bv = d2; bi = code; }
        }
        #pragma unroll
        for (int off = 1; off < 16; off <<= 1){
          float ov = __shfl_xor(bv, off, 16);
          int   oi = __shfl_xor(bi, off, 16);
          if (ov < bv || (ov == bv && oi < bi)){ bv = ov; bi = oi; }
        }
        if (li == 0){
          if (bv < bestV[cH][row] || (bv == bestV[cH][row] && bi < bestI[cH][row])){
            bestV[cH][row] = bv; bestI[cH][row] = bi;
          }
        }
      }
    }
    __syncthreads();

    // collect all codes within WWIN of running global min
    #pragma unroll
    for (int mi = 0; mi < 4; mi++){
      #pragma unroll
      for (int r = 0; r < 4; r++){
        const int row = tH*64 + mi*16 + lq*4 + r;
        const float thr = fminf(bestV[0][row], bestV[1][row]) + WWIN;
        const float zn = znS[row];
        #pragma unroll
        for (int ni = 0; ni < 8; ni++){
          float t  = zn - 2.0f * acc[mi][ni][r];
          float d2 = t + cnv[ni];
          if (d2 <= thr){
            const int code = cc*256 + cH*128 + ni*16 + li;
            int pos = atomicAdd(&cnt[row], 1);
            if (pos < CCAP) cand[row*CCAP + pos] = (unsigned short)code;
          }
        }
      }
    }
    __syncthreads();
  }

  // dump: counts, provisional best, candidate lists
  if (tid < 128){
    float v0 = bestV[0][tid], v1 = bestV[1][tid];
    int   i0 = bestI[0][tid], i1 = bestI[1][tid];
    abestW[blk*128 + tid] = (v1 < v0 || (v1 == v0 && i1 < i0)) ? i1 : i0;
    cntW[blk*128 + tid] = cnt[tid];
    uint4* dst = (uint4*)&candW[(size_t)(blk*128 + tid) * CCAP];
    dst[0] = candU[tid][0];
    dst[1] = candU[tid][1];
  }
}

// ---------- phase 2: exact fp32 rescore (R3-proven arithmetic), 1 thread/token ----------
__global__ __launch_bounds__(256) void vq_rescore_k(const float* __restrict__ z,
                                                    const float* __restrict__ cb,
                                                    const float* __restrict__ cnG,
                                                    const int* __restrict__ cntW,
                                                    const unsigned short* __restrict__ candW,
                                                    const int* __restrict__ abestW,
                                                    int* __restrict__ idsW,
                                                    float* __restrict__ out){
  const int tok = blockIdx.x * 256 + threadIdx.x;
  const int b = tok >> 14, s = tok & 16383;
  const float* zr = z + (size_t)b * Dd * SPB + s;

  int n = cntW[tok];
  const bool ovf = (n > CCAP);
  if (ovf) n = CCAP;
  unsigned short cds[CCAP];
  *(uint4*)&cds[0] = *(const uint4*)&candW[(size_t)tok * CCAP];
  *(uint4*)&cds[8] = *(const uint4*)&candW[(size_t)tok * CCAP + 8];

  float bv = 3.4e38f; int bi = 0x7fffffff;
  float znl = 0.f;
  const int ngroups = (n + 3) >> 2;
  const int total = ovf ? ngroups + 1 : ngroups;

  for (int g = 0; g < total; g++){
    int idxs[4];
    #pragma unroll
    for (int ss = 0; ss < 4; ss++){
      int slot = g*4 + ss; if (slot >= n) slot = n - 1;
      idxs[ss] = (g < ngroups) ? (int)cds[slot] : abestW[tok];
    }
    const float* cr0 = cb + (size_t)idxs[0] * Dd;
    const float* cr1 = cb + (size_t)idxs[1] * Dd;
    const float* cr2 = cb + (size_t)idxs[2] * Dd;
    const float* cr3 = cb + (size_t)idxs[3] * Dd;
    float a0=0.f, a1=0.f, a2=0.f, a3=0.f, za=0.f;
    for (int d = 0; d < Dd; d += 8){
      float zv[8];
      #pragma unroll
      for (int j = 0; j < 8; j++) zv[j] = zr[(size_t)(d + j) * SPB];
      float4 c0a = *(const float4*)(cr0 + d), c0b = *(const float4*)(cr0 + d + 4);
      float4 c1a = *(const float4*)(cr1 + d), c1b = *(const float4*)(cr1 + d + 4);
      float4 c2a = *(const float4*)(cr2 + d), c2b = *(const float4*)(cr2 + d + 4);
      float4 c3a = *(const float4*)(cr3 + d), c3b = *(const float4*)(cr3 + d + 4);
      float cv0[8] = {c0a.x,c0a.y,c0a.z,c0a.w,c0b.x,c0b.y,c0b.z,c0b.w};
      float cv1[8] = {c1a.x,c1a.y,c1a.z,c1a.w,c1b.x,c1b.y,c1b.z,c1b.w};
      float cv2[8] = {c2a.x,c2a.y,c2a.z,c2a.w,c2b.x,c2b.y,c2b.z,c2b.w};
      float cv3[8] = {c3a.x,c3a.y,c3a.z,c3a.w,c3b.x,c3b.y,c3b.z,c3b.w};
      #pragma unroll
      for (int j = 0; j < 8; j++){
        if (g == 0) za = fmaf(zv[j], zv[j], za);
        a0 = fmaf(zv[j], cv0[j], a0);
        a1 = fmaf(zv[j], cv1[j], a1);
        a2 = fmaf(zv[j], cv2[j], a2);
        a3 = fmaf(zv[j], cv3[j], a3);
      }
    }
    if (g == 0) znl = za;
    float av[4] = {a0, a1, a2, a3};
    const int lim = (g < ngroups) ? n : 1;
    #pragma unroll
    for (int ss = 0; ss < 4; ss++){
      if (g*4 + ss < lim || (g >= ngroups && ss == 0)){
        float t  = znl - 2.0f * av[ss];
        float d2 = t + cnG[idxs[ss]];
        if (d2 < bv || (d2 == bv && idxs[ss] < bi)){ bv = d2; bi = idxs[ss]; }
      }
    }
  }
  idsW[tok] = bi;
  out[(size_t)2 * Nn * Dd + tok] = (float)bi;
}

// ---------- phase 3: LDS-transpose gather ----------
__global__ __launch_bounds__(256) void vq_gather_k(const float* __restrict__ cb,
                                                   const int* __restrict__ idsW,
                                                   float* __restrict__ out){
  __shared__ float tile[64][129];
  __shared__ int lid[64];
  const int tid = threadIdx.x, blk = blockIdx.x;   // 2048 blocks
  const int b = blk >> 8, s0 = (blk & 255) * 64;
  if (tid < 64) lid[tid] = idsW[b * SPB + s0 + tid];
  __syncthreads();

  const int r2 = tid >> 7, c = tid & 127;          // load mapping
  const int s = tid & 63, cq = tid >> 6;           // store mapping
  float* qb  = out + (size_t)b * Dd * SPB + s0 + s;
  float* stb = qb + (size_t)Nn * Dd;

  for (int ch = 0; ch < 2; ch++){
    #pragma unroll 4
    for (int t0 = 0; t0 < 64; t0 += 2){
      const int row = t0 + r2;
      tile[row][c] = cb[(size_t)lid[row] * Dd + ch*128 + c];
    }
    __syncthreads();
    #pragma unroll 8
    for (int i = 0; i < 32; i++){
      const int cc2 = i*4 + cq;
      const float v = tile[s][cc2];
      const size_t off = (size_t)(ch*128 + cc2) * SPB;
      qb[off]  = v;
      stb[off] = v;
    }
    __syncthreads();
  }
}

// ================= R1 fp32 fallback (used if ws too small) =================
#define MICRO_STEP(WITH_ZN)                                                    \
    {                                                                          \
        float4 a0 = *(const float4*)&As[d][ty * 8];                            \
        float4 a1 = *(const float4*)&As[d][ty * 8 + 4];                        \
        float4 b0 = *(const float4*)&Bs[d][tx * 8];                            \
        float4 b1 = *(const float4*)&Bs[d][tx * 8 + 4];                        \
        float a[8] = {a0.x, a0.y, a0.z, a0.w, a1.x, a1.y, a1.z, a1.w};         \
        float bb[8] = {b0.x, b0.y, b0.z, b0.w, b1.x, b1.y, b1.z, b1.w};        \
        _Pragma("unroll")                                                      \
        for (int i = 0; i < 8; i++) {                                          \
            _Pragma("unroll")                                                  \
            for (int j = 0; j < 8; j++) acc[i][j] += a[i] * bb[j];             \
            if (WITH_ZN) zn[i] += a[i] * a[i];                                 \
        }                                                                      \
    }

__global__ __launch_bounds__(256) void vq_k(const float* __restrict__ z,
                                            const float* __restrict__ cb,
                                            const float* __restrict__ cn,
                                            float* __restrict__ out){
  __shared__ float As[16][128];
  __shared__ float Bs[16][132];
  __shared__ int   idsf[128];
  const int tid = threadIdx.x;
  const int tx = tid & 15, ty = tid >> 4;
  const int blk = blockIdx.x;
  const int b = blk >> 7, sb = (blk & 127) * 128;
  const float* zb = z + (size_t)b * Dd * SPB + sb;
  float bestv[8]; int besti[8]; float zn[8];
  #pragma unroll
  for (int i = 0; i < 8; i++){ bestv[i] = 3.4e38f; besti[i] = 0; zn[i] = 0.f; }
  const int am = tid & 127, ad = tid >> 7;
  const int bd = tid & 15,  bk = tid >> 4;
  for (int cc = 0; cc < 8; cc++){
    float acc[8][8];
    #pragma unroll
    for (int i = 0; i < 8; i++)
      #pragma unroll
      for (int j = 0; j < 8; j++) acc[i][j] = 0.f;
    for (int dc = 0; dc < 16; dc++){
      #pragma unroll
      for (int r = 0; r < 8; r++){
        const int d = ad + r * 2;
        As[d][am] = zb[(size_t)(dc*16 + d) * SPB + am];
      }
      #pragma unroll
      for (int r = 0; r < 8; r++){
        const int k = bk + r * 16;
        Bs[bd][k] = cb[(size_t)(cc*128 + k) * Dd + dc*16 + bd];
      }
      __syncthreads();
      if (cc == 0){
        #pragma unroll
        for (int d = 0; d < 16; d++) MICRO_STEP(1)
      } else {
        #pragma unroll
        for (int d = 0; d < 16; d++) MICRO_STEP(0)
      }
      __syncthreads();
    }
    const float* cnp = cn + cc*128 + tx*8;
    float4 c0 = *(const float4*)cnp;
    float4 c1 = *(const float4*)(cnp + 4);
    float cv[8] = {c0.x, c0.y, c0.z, c0.w, c1.x, c1.y, c1.z, c1.w};
    #pragma unroll
    for (int i = 0; i < 8; i++){
      #pragma unroll
      for (int j = 0; j < 8; j++){
        float t  = zn[i] - 2.0f * acc[i][j];
        float d2 = t + cv[j];
        int   ix = cc*128 + tx*8 + j;
        if (d2 < bestv[i]){ bestv[i] = d2; besti[i] = ix; }
      }
    }
  }
  #pragma unroll
  for (int i = 0; i < 8; i++){
    float v = bestv[i]; int ix = besti[i];
    #pragma unroll
    for (int off = 8; off > 0; off >>= 1){
      float ov = __shfl_down(v, off, 16);
      int   oi = __shfl_down(ix, off, 16);
      if (ov < v || (ov == v && oi < ix)){ v = ov; ix = oi; }
    }
    if (tx == 0) idsf[ty*8 + i] = ix;
  }
  __syncthreads();
  if (tid < 128) out[(size_t)2*Nn*Dd + (size_t)blk*128 + tid] = (float)idsf[tid];
  const int m = tid & 127, cg = tid >> 7;
  const int myidx = idsf[m];
  const float* crow = cb + (size_t)myidx * Dd + cg*128;
  float* q  = out + (size_t)b * Dd * SPB + (size_t)cg * 128 * SPB + sb + m;
  float* st = q + (size_t)Nn * Dd;
  #pragma unroll 8
  for (int r = 0; r < 128; r++){
    const float v = crow[r];
    q[(size_t)r * SPB]  = v;
    st[(size_t)r * SPB] = v;
  }
}

// ---------- launcher ----------
extern "C" void kernel_launch(void* const* d_in, const int* in_sizes, int n_in,
                              void* d_out, int out_size, void* d_ws, size_t ws_size,
                              hipStream_t stream){
  const float* z  = (const float*)d_in[0];
  const float* cb = (const float*)d_in[1];
  float* out = (float*)d_out;

  const size_t AG_B  = (size_t)1024 * 8 * 512 * 16;   // 64 MiB
  const size_t BG_B  = (size_t)4 * 8 * 1024 * 16;     // 512 KiB
  const size_t ZN_B  = (size_t)Nn * 4;                // 512 KiB
  const size_t CN_B  = (size_t)Kk * 4;                // 4 KiB
  const size_t CNT_B = (size_t)Nn * 4;                // 512 KiB
  const size_t CAN_B = (size_t)Nn * CCAP * 2;         // 4 MiB
  const size_t ABW_B = (size_t)Nn * 4;                // 512 KiB
  const size_t IDS_B = (size_t)Nn * 4;                // 512 KiB
  const size_t NEED = AG_B + BG_B + ZN_B + CN_B + CNT_B + CAN_B + ABW_B + IDS_B;

  if (ws_size >= NEED){
    uint8_t* ws = (uint8_t*)d_ws;
    size_t o = 0;
    uint4* Ag   = (uint4*)(ws + o);          o += AG_B;
    uint4* Bg   = (uint4*)(ws + o);          o += BG_B;
    float* znG  = (float*)(ws + o);          o += ZN_B;
    float* cnG  = (float*)(ws + o);          o += CN_B;
    int*   cntW = (int*)(ws + o);            o += CNT_B;
    unsigned short* candW = (unsigned short*)(ws + o); o += CAN_B;
    int*   abW  = (int*)(ws + o);            o += ABW_B;
    int*   idsW = (int*)(ws + o);            o += IDS_B;

    cnorm_k<<<Kk, 64, 0, stream>>>(cb, cnG);
    cconv_k<<<4, 256, 0, stream>>>(cb, Bg);
    zconv_k<<<Nn/128, 256, 0, stream>>>(z, Ag, znG);
    vq_sweep_k<<<Nn/128, 256, 0, stream>>>(Ag, Bg, znG, cnG, cntW, candW, abW);
    vq_rescore_k<<<Nn/256, 256, 0, stream>>>(z, cb, cnG, cntW, candW, abW, idsW, out);
    vq_gather_k<<<Nn/64, 256, 0, stream>>>(cb, idsW, out);
  } else {
    float* cn = (float*)d_ws;
    cnorm_k<<<Kk, 64, 0, stream>>>(cb, cn);
    vq_k<<<Nn/128, 256, 0, stream>>>(z, cb, cn, out);
  }
}